// Round 3
// baseline (1986.442 us; speedup 1.0000x reference)
//
#include <hip/hip_runtime.h>
#include <hip/hip_bf16.h>

// ---------------- problem constants ----------------
#define TOK 16384     // B*S
#define DD  2048      // D
#define HH  1024      // D/2
#define NDIM 64       // noise dim
// d_out section offsets (floats): out | noise | mean | log_var
#define NOISE_OFF 33554432
#define MEAN_OFF  34603008
#define LV_OFF    35651584

// ---------------- workspace layout (bytes) ----------------
// WCH/WCL: cls_w1^T hi/lo bf16 [1024][2048]
// WVH:     var_w1^T hi bf16    [1024][2048]
// WD:      dec_w2^T bf16       [3][2048(n)][2048(k)]
// W1T:     dec_w1^T bf16       [3][2048(c)][64(k)]
// LOGP:    cls logit partials  [16][16384][3] f32 (slot-indexed, no atomics)
// VARP:    var logit partials  [16][16384] f32
#define WS_WCH  0u
#define WS_WCL  4194304u
#define WS_WVH  8388608u
#define WS_WD   12582912u
#define WS_W1T  37748736u
#define WS_LOGP 38535168u
#define WS_VARP 41680896u
#define WS_STR  42729472u
#define WS_CNT  42795008u
#define WS_LIST 42795264u
#define WS_NZ   42991872u
// total ~45.1 MB

typedef float f32x4 __attribute__((ext_vector_type(4)));
typedef short short8 __attribute__((ext_vector_type(8)));

__device__ __forceinline__ f32x4 MFMA(uint4 a, uint4 b, f32x4 c) {
  return __builtin_amdgcn_mfma_f32_16x16x32_bf16(
      __builtin_bit_cast(short8, a), __builtin_bit_cast(short8, b), c, 0, 0, 0);
}

__device__ __forceinline__ unsigned short f2b(float f) {
  __hip_bfloat16 h = __float2bfloat16(f);
  return __builtin_bit_cast(unsigned short, h);
}
__device__ __forceinline__ float b2f(unsigned short u) {
  return __bfloat162float(__builtin_bit_cast(__hip_bfloat16, u));
}
__device__ __forceinline__ float siluf(float h) { return h / (1.f + expf(-h)); }

// ---------------- T1: transpose+split router weights ----------------
// src [2048(k)][1024(n)] f32 -> dst [1024(n)][2048(k)] bf16 hi (+lo for cls)
__global__ __launch_bounds__(256) void t_router_w(
    const float* __restrict__ cls_w1, const float* __restrict__ var_w1,
    unsigned short* __restrict__ wch, unsigned short* __restrict__ wcl,
    unsigned short* __restrict__ wvh) {
  __shared__ float tile[32][33];
  int z = blockIdx.z;
  const float* src = z ? var_w1 : cls_w1;
  int k0 = blockIdx.x * 32, n0 = blockIdx.y * 32;
  int tid = threadIdx.x;
#pragma unroll
  for (int p = 0; p < 4; ++p) {
    int idx = tid + p * 256; int kk = idx >> 5, nn = idx & 31;
    tile[kk][nn] = src[(size_t)(k0 + kk) * HH + (n0 + nn)];
  }
  __syncthreads();
#pragma unroll
  for (int p = 0; p < 4; ++p) {
    int idx = tid + p * 256; int kk = idx & 31, nn = idx >> 5;
    float v = tile[kk][nn];
    size_t o = (size_t)(n0 + nn) * DD + (k0 + kk);
    unsigned short h = f2b(v);
    if (z == 0) { wch[o] = h; wcl[o] = f2b(v - b2f(h)); }
    else        { wvh[o] = h; }
  }
}

// ---------------- T2: transpose dec_w2 -> [e][n][k] bf16 ----------------
__global__ __launch_bounds__(256) void t_dec_w(
    const float* __restrict__ dec_w2, unsigned short* __restrict__ wd) {
  __shared__ float tile[32][33];
  int e = blockIdx.z;
  const float* src = dec_w2 + (size_t)e * DD * DD;
  unsigned short* dst = wd + (size_t)e * DD * DD;
  int k0 = blockIdx.x * 32, n0 = blockIdx.y * 32;
  int tid = threadIdx.x;
#pragma unroll
  for (int p = 0; p < 4; ++p) {
    int idx = tid + p * 256; int kk = idx >> 5, nn = idx & 31;
    tile[kk][nn] = src[(size_t)(k0 + kk) * DD + (n0 + nn)];
  }
  __syncthreads();
#pragma unroll
  for (int p = 0; p < 4; ++p) {
    int idx = tid + p * 256; int kk = idx & 31, nn = idx >> 5;
    dst[(size_t)(n0 + nn) * DD + (k0 + kk)] = f2b(tile[kk][nn]);
  }
}

// ---------------- T3: transpose dec_w1 [e][64][2048] -> w1t [e][2048][64] bf16 ----------------
__global__ __launch_bounds__(256) void t_dec_w1(
    const float* __restrict__ dec_w1, unsigned short* __restrict__ w1t) {
  __shared__ float tile[32][33];
  int e = blockIdx.z;
  const float* src = dec_w1 + (size_t)e * NDIM * DD;
  unsigned short* dst = w1t + (size_t)e * DD * NDIM;
  int k0 = blockIdx.x * 32, c0 = blockIdx.y * 32;
  int tid = threadIdx.x;
#pragma unroll
  for (int p = 0; p < 4; ++p) {
    int idx = tid + p * 256; int kk = idx >> 5, nn = idx & 31;
    tile[kk][nn] = src[(size_t)(k0 + kk) * DD + (c0 + nn)];
  }
  __syncthreads();
#pragma unroll
  for (int p = 0; p < 4; ++p) {
    int idx = tid + p * 256; int kk = idx & 31, nn = idx >> 5;
    dst[(size_t)(c0 + nn) * NDIM + (k0 + kk)] = f2b(tile[kk][nn]);
  }
}

// ---------------- K1: merged router GEMM (3-term compensated bf16 MFMA + var) ----------------
// grid 1024: mt = bx>>2 (64-token row group), nblk = bx&3 (256-col slice).
// cls: xh*wh + xl*wh + xh*wl (residual ~2^-18, below f32 accum noise).
// var: xh*wh only. A staged in LDS subtiled-linear [64 rows][32 k] (conflict-free).
// Fused layer-2 epilogue writes slot-indexed partials (deterministic).
__global__ __launch_bounds__(256, 2) void k_router(
    const float* __restrict__ x,
    const float* __restrict__ cls_b1, const float* __restrict__ cls_w2,
    const float* __restrict__ var_b1, const float* __restrict__ var_w2,
    const unsigned short* __restrict__ wch, const unsigned short* __restrict__ wcl,
    const unsigned short* __restrict__ wvh,
    float* __restrict__ logp, float* __restrict__ varp) {
  __shared__ unsigned short AH[64 * 32];
  __shared__ unsigned short AL[64 * 32];
  int bx = blockIdx.x;
  int mt = bx >> 2, nblk = bx & 3;
  int rowbase = mt * 64;
  int tid = threadIdx.x;
  int lane = tid & 63, wave = tid >> 6;
  int arl = lane & 15, kg = lane >> 4;
  int colw = nblk * 256 + wave * 64;
  f32x4 accC[4][4], accV[4][4];
#pragma unroll
  for (int a = 0; a < 4; ++a)
#pragma unroll
    for (int b = 0; b < 4; ++b) { accC[a][b] = (f32x4)0.f; accV[a][b] = (f32x4)0.f; }
  int srow = tid >> 2, ks = tid & 3;
  const float* xrow = x + (size_t)(rowbase + srow) * DD + ks * 8;
  unsigned short* wrH = &AH[srow * 32 + ks * 8];
  unsigned short* wrL = &AL[srow * 32 + ks * 8];

  for (int k0 = 0; k0 < DD; k0 += 32) {
    float4 v0 = *(const float4*)(xrow + k0);
    float4 v1 = *(const float4*)(xrow + k0 + 4);
    float vv[8] = {v0.x, v0.y, v0.z, v0.w, v1.x, v1.y, v1.z, v1.w};
    union { unsigned short u[8]; uint4 q; } ph, pl;
#pragma unroll
    for (int j = 0; j < 8; ++j) {
      unsigned short h = f2b(vv[j]);
      ph.u[j] = h;
      pl.u[j] = f2b(vv[j] - b2f(h));
    }
    *(uint4*)wrH = ph.q;
    *(uint4*)wrL = pl.q;
    __syncthreads();
    uint4 ah[4], al[4];
#pragma unroll
    for (int rt = 0; rt < 4; ++rt) {
      ah[rt] = *(const uint4*)&AH[(rt * 16 + arl) * 32 + kg * 8];
      al[rt] = *(const uint4*)&AL[(rt * 16 + arl) * 32 + kg * 8];
    }
#pragma unroll
    for (int nt = 0; nt < 4; ++nt) {
      int col = colw + nt * 16 + arl;
      size_t bo = (size_t)col * DD + k0 + kg * 8;
      uint4 bh = *(const uint4*)(wch + bo);
      uint4 bl = *(const uint4*)(wcl + bo);
      uint4 bv = *(const uint4*)(wvh + bo);
#pragma unroll
      for (int rt = 0; rt < 4; ++rt) {
        accC[rt][nt] = MFMA(ah[rt], bh, accC[rt][nt]);
        accC[rt][nt] = MFMA(al[rt], bh, accC[rt][nt]);
        accC[rt][nt] = MFMA(ah[rt], bl, accC[rt][nt]);
        accV[rt][nt] = MFMA(ah[rt], bv, accV[rt][nt]);
      }
    }
    __syncthreads();
  }

  float part[4][4][3], pv[4][4];
#pragma unroll
  for (int rt = 0; rt < 4; ++rt)
#pragma unroll
    for (int r = 0; r < 4; ++r) {
      part[rt][r][0] = 0.f; part[rt][r][1] = 0.f; part[rt][r][2] = 0.f;
      pv[rt][r] = 0.f;
    }
#pragma unroll
  for (int nt = 0; nt < 4; ++nt) {
    int colg = colw + nt * 16 + arl;
    float bbc = cls_b1[colg];
    float w0 = cls_w2[colg * 3 + 0];
    float w1v = cls_w2[colg * 3 + 1];
    float w2v = cls_w2[colg * 3 + 2];
    float bbv = var_b1[colg];
    float wv = var_w2[colg];
#pragma unroll
    for (int rt = 0; rt < 4; ++rt)
#pragma unroll
      for (int r = 0; r < 4; ++r) {
        float s = siluf(accC[rt][nt][r] + bbc);
        part[rt][r][0] += s * w0;
        part[rt][r][1] += s * w1v;
        part[rt][r][2] += s * w2v;
        pv[rt][r] += siluf(accV[rt][nt][r] + bbv) * wv;
      }
  }
  for (int m = 1; m < 16; m <<= 1)
#pragma unroll
    for (int rt = 0; rt < 4; ++rt)
#pragma unroll
      for (int r = 0; r < 4; ++r) {
        part[rt][r][0] += __shfl_xor(part[rt][r][0], m);
        part[rt][r][1] += __shfl_xor(part[rt][r][1], m);
        part[rt][r][2] += __shfl_xor(part[rt][r][2], m);
        pv[rt][r] += __shfl_xor(pv[rt][r], m);
      }
  if (arl == 0) {
    int slot = nblk * 4 + wave;
#pragma unroll
    for (int rt = 0; rt < 4; ++rt)
#pragma unroll
      for (int r = 0; r < 4; ++r) {
        int row = rowbase + rt * 16 + kg * 4 + r;
        size_t o = (size_t)slot * TOK + row;
        logp[o * 3 + 0] = part[rt][r][0];
        logp[o * 3 + 1] = part[rt][r][1];
        logp[o * 3 + 2] = part[rt][r][2];
        varp[o] = pv[rt][r];
      }
  }
}

// ---------------- K2: deterministic reduce + argmax + strength + buckets ----------------
__global__ __launch_bounds__(256) void k_select(
    const float* __restrict__ logp, const float* __restrict__ varp,
    const float* __restrict__ cls_b2, const float* __restrict__ var_b2,
    float* __restrict__ strength, int* __restrict__ cnt, int* __restrict__ list) {
  int t = blockIdx.x * 256 + threadIdx.x;
  if (t >= TOK) return;
  float l0 = cls_b2[0], l1 = cls_b2[1], l2 = cls_b2[2];
  float vv = var_b2[0];
#pragma unroll
  for (int s = 0; s < 16; ++s) {
    size_t o = (size_t)s * TOK + t;
    l0 += logp[o * 3 + 0];
    l1 += logp[o * 3 + 1];
    l2 += logp[o * 3 + 2];
    vv += varp[o];
  }
  int best = 0; float bl = l0;
  if (l1 > bl) { best = 1; bl = l1; }
  if (l2 > bl) { best = 2; bl = l2; }
  int pos = atomicAdd(&cnt[best], 1);
  list[best * TOK + pos] = t;
  strength[t] = 1.f / (1.f + expf(-vv));
}

// ---------------- K3: encoder (selected expert only, bucketed) ----------------
__global__ __launch_bounds__(256) void k_encode(
    const float* __restrict__ x, const float* __restrict__ eps,
    const float* __restrict__ enc_w1, const float* __restrict__ enc_b1,
    const float* __restrict__ enc_w2, const float* __restrict__ enc_b2,
    const int* __restrict__ cnt, const int* __restrict__ list,
    float* __restrict__ out, unsigned short* __restrict__ nzbf) {
  __shared__ unsigned short xl[8][2048];
  __shared__ float part[4][512];
  __shared__ float hls[8][64];
  __shared__ float pls[8][128];
  __shared__ int toks[8];
  __shared__ int es[8];
  int tid = threadIdx.x;
  if (tid < 8) {
    int slot = blockIdx.x * 8 + tid;
    int c0 = cnt[0], c1 = cnt[1];
    int e, idx;
    if (slot < c0)            { e = 0; idx = slot; }
    else if (slot < c0 + c1)  { e = 1; idx = slot - c0; }
    else                      { e = 2; idx = slot - c0 - c1; }
    toks[tid] = list[e * TOK + idx];
    es[tid] = e;
  }
  __syncthreads();
  bool uni = true;
  int e0 = es[0];
#pragma unroll
  for (int r = 1; r < 8; ++r) uni = uni && (es[r] == e0);
#pragma unroll
  for (int r = 0; r < 8; ++r) {
    const float4* xr = (const float4*)(x + (size_t)toks[r] * DD);
#pragma unroll
    for (int i = 0; i < 2; ++i) {
      int kq = tid + i * 256;
      float4 v = xr[kq];
      union { unsigned short u[4]; unsigned long long q; } p;
      p.u[0] = f2b(v.x); p.u[1] = f2b(v.y); p.u[2] = f2b(v.z); p.u[3] = f2b(v.w);
      *(unsigned long long*)(&xl[r][kq * 4]) = p.q;
    }
  }
  __syncthreads();
  int n = tid & 63, q = tid >> 6;
  float acc[8];
#pragma unroll
  for (int r = 0; r < 8; ++r) acc[r] = 0.f;
  if (uni) {
    const float* w = enc_w1 + (size_t)e0 * DD * NDIM;
    for (int kk = 0; kk < 512; ++kk) {
      int k = q * 512 + kk;
      float wv = w[k * NDIM + n];
#pragma unroll
      for (int r = 0; r < 8; ++r) acc[r] += b2f(xl[r][k]) * wv;
    }
  } else {
#pragma unroll
    for (int r = 0; r < 8; ++r) {
      const float* w = enc_w1 + (size_t)es[r] * DD * NDIM;
      float a = 0.f;
      for (int kk = 0; kk < 512; ++kk) {
        int k = q * 512 + kk;
        a += b2f(xl[r][k]) * w[k * NDIM + n];
      }
      acc[r] = a;
    }
  }
#pragma unroll
  for (int r = 0; r < 8; ++r) part[q][r * 64 + n] = acc[r];
  __syncthreads();
#pragma unroll
  for (int it = 0; it < 2; ++it) {
    int o = tid + it * 256; int r = o >> 6, n2 = o & 63; int e = es[r];
    float h = part[0][o] + part[1][o] + part[2][o] + part[3][o] + enc_b1[e * 64 + n2];
    hls[r][n2] = siluf(h);
  }
  __syncthreads();
#pragma unroll
  for (int it = 0; it < 4; ++it) {
    int o = tid + it * 256; int r = o >> 7, j = o & 127; int e = es[r];
    const float* w2 = enc_w2 + e * 64 * 128;
    float a = 0.f;
#pragma unroll
    for (int nn = 0; nn < 64; ++nn) a += hls[r][nn] * w2[nn * 128 + j];
    pls[r][j] = a + enc_b2[e * 128 + j];
  }
  __syncthreads();
#pragma unroll
  for (int it = 0; it < 2; ++it) {
    int o = tid + it * 256; int r = o >> 6, j = o & 63; int t = toks[r];
    float m = pls[r][j], lv = pls[r][64 + j];
    float nz = eps[(size_t)t * 64 + j] * expf(0.5f * lv) + m;
    out[NOISE_OFF + (size_t)t * 64 + j] = nz;
    out[MEAN_OFF + (size_t)t * 64 + j] = m;
    out[LV_OFF + (size_t)t * 64 + j] = lv;
    nzbf[t * 64 + j] = f2b(nz);
  }
}

// ---------------- K4: decoder — MFMA dh-build + grouped GEMM + fused LN ----------------
// grid 2048, XCD-affine: e = (bx&7)*3>>3 so each XCD mostly serves one expert's
// dec_w2 slice (L2 reuse). 32 tokens/block, full N=2048.
// dh LDS layout subtiled-linear [64 ktiles][32 rows][32 k] -> conflict-free b128.
__global__ __launch_bounds__(512, 2) void k_decode(
    const float* __restrict__ x,
    const float* __restrict__ dec_b1, const float* __restrict__ dec_b2,
    const float* __restrict__ ln_g, const float* __restrict__ ln_b,
    const unsigned short* __restrict__ w1t, const unsigned short* __restrict__ wd,
    const unsigned short* __restrict__ nzbf,
    const int* __restrict__ cnt, const int* __restrict__ list,
    const float* __restrict__ strength, float* __restrict__ out) {
  int bx = blockIdx.x;
  int x7 = bx & 7;
  int e = (x7 * 3) >> 3;
  int idx = x7 - (e == 0 ? 0 : (e == 1 ? 3 : 6));
  int we = (e == 2) ? 2 : 3;
  int mt = (bx >> 3) * we + idx;
  int cnte = cnt[e];
  int base = mt * 32;
  if (base >= cnte) return;
  __shared__ unsigned short dhs[65536];   // 128 KB: [64][32][32] bf16
  __shared__ unsigned short nzs[2048];    // [2][32][32] bf16
  __shared__ float sums[32][2];
  __shared__ int tokv[32];
  __shared__ int vld[32];
  int tid = threadIdx.x;
  int lane = tid & 63, wave = tid >> 6;
  int arl = lane & 15, kg = lane >> 4;
  int colbase = wave * 256;
  if (tid < 32) {
    int s = base + tid;
    int ok = (s < cnte) ? 1 : 0;
    vld[tid] = ok;
    tokv[tid] = list[e * TOK + (ok ? s : base)];
  }
  __syncthreads();
#pragma unroll
  for (int i = 0; i < 4; ++i) {
    int o = tid + i * 512; int r = o >> 6, k = o & 63;
    nzs[(k >> 5) * 1024 + r * 32 + (k & 31)] = nzbf[(size_t)tokv[r] * 64 + k];
  }
  __syncthreads();
  // ---- dh = silu(nz @ dec_w1 + b1) via MFMA ----
  const unsigned short* w1e = w1t + (size_t)e * DD * NDIM;
  const float* b1 = dec_b1 + (size_t)e * DD;
  float b1v[16];
#pragma unroll
  for (int nt = 0; nt < 16; ++nt) b1v[nt] = b1[colbase + nt * 16 + arl];
  {
    f32x4 acch[2][16];
#pragma unroll
    for (int rt = 0; rt < 2; ++rt)
#pragma unroll
      for (int nt = 0; nt < 16; ++nt) acch[rt][nt] = (f32x4)0.f;
#pragma unroll
    for (int h = 0; h < 2; ++h) {
      uint4 a0 = *(const uint4*)&nzs[h * 1024 + arl * 32 + kg * 8];
      uint4 a1 = *(const uint4*)&nzs[h * 1024 + (16 + arl) * 32 + kg * 8];
#pragma unroll
      for (int nt = 0; nt < 16; ++nt) {
        int col = colbase + nt * 16 + arl;
        uint4 b = *(const uint4*)(w1e + (size_t)col * NDIM + h * 32 + kg * 8);
        acch[0][nt] = MFMA(a0, b, acch[0][nt]);
        acch[1][nt] = MFMA(a1, b, acch[1][nt]);
      }
    }
#pragma unroll
    for (int rt = 0; rt < 2; ++rt)
#pragma unroll
      for (int nt = 0; nt < 16; ++nt) {
        int c = colbase + nt * 16 + arl;
#pragma unroll
        for (int r = 0; r < 4; ++r) {
          int row = rt * 16 + kg * 4 + r;
          float s = siluf(acch[rt][nt][r] + b1v[nt]);
          dhs[(c >> 5) * 1024 + row * 32 + (c & 31)] = f2b(s);
        }
      }
  }
  __syncthreads();
  // ---- do = dh @ dec_w2^T (MFMA); wave owns 256 unique cols, both row-tiles ----
  const unsigned short* Bt = wd + (size_t)e * DD * DD;
  f32x4 acc[2][16];
#pragma unroll
  for (int rt = 0; rt < 2; ++rt)
#pragma unroll
    for (int nt = 0; nt < 16; ++nt) acc[rt][nt] = (f32x4)0.f;
  for (int k0 = 0; k0 < DD; k0 += 32) {
    int tilo = (k0 >> 5) * 1024;
    uint4 af0 = *(const uint4*)&dhs[tilo + arl * 32 + kg * 8];
    uint4 af1 = *(const uint4*)&dhs[tilo + (16 + arl) * 32 + kg * 8];
    int kb = k0 + kg * 8;
#pragma unroll
    for (int nt = 0; nt < 16; ++nt) {
      int col = colbase + nt * 16 + arl;
      uint4 b = *(const uint4*)(Bt + (size_t)col * DD + kb);
      acc[0][nt] = MFMA(af0, b, acc[0][nt]);
      acc[1][nt] = MFMA(af1, b, acc[1][nt]);
    }
  }
  __syncthreads();
  if (tid < 64) sums[tid >> 1][tid & 1] = 0.f;
  __syncthreads();
  // ---- LayerNorm stats ----
  const float* b2 = dec_b2 + (size_t)e * DD;
  float s1[2][4], s2[2][4];
#pragma unroll
  for (int rt = 0; rt < 2; ++rt)
#pragma unroll
    for (int r = 0; r < 4; ++r) { s1[rt][r] = 0.f; s2[rt][r] = 0.f; }
#pragma unroll
  for (int nt = 0; nt < 16; ++nt) {
    int col = colbase + nt * 16 + arl;
    float bbv = b2[col];
#pragma unroll
    for (int rt = 0; rt < 2; ++rt)
#pragma unroll
      for (int r = 0; r < 4; ++r) {
        float v = acc[rt][nt][r] + bbv;
        acc[rt][nt][r] = v;
        s1[rt][r] += v;
        s2[rt][r] += v * v;
      }
  }
  for (int m = 1; m < 16; m <<= 1)
#pragma unroll
    for (int rt = 0; rt < 2; ++rt)
#pragma unroll
      for (int r = 0; r < 4; ++r) {
        s1[rt][r] += __shfl_xor(s1[rt][r], m);
        s2[rt][r] += __shfl_xor(s2[rt][r], m);
      }
  if (arl == 0) {
#pragma unroll
    for (int rt = 0; rt < 2; ++rt)
#pragma unroll
      for (int r = 0; r < 4; ++r) {
        int row = rt * 16 + kg * 4 + r;
        atomicAdd(&sums[row][0], s1[rt][r]);
        atomicAdd(&sums[row][1], s2[rt][r]);
      }
  }
  __syncthreads();
  float mu[2][4], rs[2][4], strv[2][4]; size_t xoff[2][4]; int okr[2][4];
#pragma unroll
  for (int rt = 0; rt < 2; ++rt)
#pragma unroll
    for (int r = 0; r < 4; ++r) {
      int row = rt * 16 + kg * 4 + r;
      float m1 = sums[row][0] * (1.f / 2048.f);
      float var = sums[row][1] * (1.f / 2048.f) - m1 * m1;
      mu[rt][r] = m1;
      rs[rt][r] = rsqrtf(var + 1e-5f);
      int t = tokv[row];
      okr[rt][r] = vld[row];
      strv[rt][r] = strength[t];
      xoff[rt][r] = (size_t)t * DD;
    }
#pragma unroll
  for (int nt = 0; nt < 16; ++nt) {
    int col = colbase + nt * 16 + arl;
    float g = ln_g[e * DD + col], bv = ln_b[e * DD + col];
#pragma unroll
    for (int rt = 0; rt < 2; ++rt)
#pragma unroll
      for (int r = 0; r < 4; ++r) {
        if (okr[rt][r]) {
          float nvv = (acc[rt][nt][r] - mu[rt][r]) * rs[rt][r];
          out[xoff[rt][r] + col] = x[xoff[rt][r] + col] + strv[rt][r] * (nvv * g + bv);
        }
      }
  }
}

// ---------------- launch ----------------
extern "C" void kernel_launch(void* const* d_in, const int* in_sizes, int n_in,
                              void* d_out, int out_size, void* d_ws, size_t ws_size,
                              hipStream_t stream) {
  const float* x      = (const float*)d_in[0];
  const float* eps    = (const float*)d_in[1];
  const float* cls_w1 = (const float*)d_in[2];
  const float* cls_b1 = (const float*)d_in[3];
  const float* cls_w2 = (const float*)d_in[4];
  const float* cls_b2 = (const float*)d_in[5];
  const float* var_w1 = (const float*)d_in[6];
  const float* var_b1 = (const float*)d_in[7];
  const float* var_w2 = (const float*)d_in[8];
  const float* var_b2 = (const float*)d_in[9];
  const float* enc_w1 = (const float*)d_in[10];
  const float* enc_b1 = (const float*)d_in[11];
  const float* enc_w2 = (const float*)d_in[12];
  const float* enc_b2 = (const float*)d_in[13];
  const float* dec_w1 = (const float*)d_in[14];
  const float* dec_b1 = (const float*)d_in[15];
  const float* dec_w2 = (const float*)d_in[16];
  const float* dec_b2 = (const float*)d_in[17];
  const float* ln_g   = (const float*)d_in[18];
  const float* ln_b   = (const float*)d_in[19];
  float* out = (float*)d_out;
  char* ws = (char*)d_ws;
  unsigned short* wch  = (unsigned short*)(ws + WS_WCH);
  unsigned short* wcl  = (unsigned short*)(ws + WS_WCL);
  unsigned short* wvh  = (unsigned short*)(ws + WS_WVH);
  unsigned short* wd   = (unsigned short*)(ws + WS_WD);
  unsigned short* w1t  = (unsigned short*)(ws + WS_W1T);
  float* logp = (float*)(ws + WS_LOGP);
  float* varp = (float*)(ws + WS_VARP);
  float* str  = (float*)(ws + WS_STR);
  int* cnt    = (int*)(ws + WS_CNT);
  int* list   = (int*)(ws + WS_LIST);
  unsigned short* nzbf = (unsigned short*)(ws + WS_NZ);

  hipMemsetAsync(ws + WS_CNT, 0, 256, stream);

  hipLaunchKernelGGL(t_router_w, dim3(64, 32, 2), dim3(256), 0, stream,
                     cls_w1, var_w1, wch, wcl, wvh);
  hipLaunchKernelGGL(t_dec_w, dim3(64, 64, 3), dim3(256), 0, stream, dec_w2, wd);
  hipLaunchKernelGGL(t_dec_w1, dim3(2, 64, 3), dim3(256), 0, stream, dec_w1, w1t);
  hipLaunchKernelGGL(k_router, dim3(1024), dim3(256), 0, stream,
                     x, cls_b1, cls_w2, var_b1, var_w2, wch, wcl, wvh, logp, varp);
  hipLaunchKernelGGL(k_select, dim3(64), dim3(256), 0, stream,
                     logp, varp, cls_b2, var_b2, str, cnt, list);
  hipLaunchKernelGGL(k_encode, dim3(2048), dim3(256), 0, stream,
                     x, eps, enc_w1, enc_b1, enc_w2, enc_b2, cnt, list, out, nzbf);
  hipLaunchKernelGGL(k_decode, dim3(2048), dim3(512), 0, stream,
                     x, dec_b1, dec_b2, ln_g, ln_b, w1t, wd, nzbf, cnt, list, str, out);
}

// Round 5
// 1659.373 us; speedup vs baseline: 1.1971x; 1.1971x over previous
//
#include <hip/hip_runtime.h>
#include <hip/hip_bf16.h>

// ---------------- problem constants ----------------
#define TOK 16384     // B*S
#define DD  2048      // D
#define HH  1024      // D/2
#define NDIM 64       // noise dim
// d_out section offsets (floats): out | noise | mean | log_var
#define NOISE_OFF 33554432
#define MEAN_OFF  34603008
#define LV_OFF    35651584

// ---------------- NEW workspace layout (bytes), needs ~103 MB ----------------
// dhg [16896][2048] bf16 @0; router scratch overlays the dhg region (dead
// before k_dh writes it).
#define WS_DHG   0u
#define WS_WCH   0u          // cls_w1^T hi bf16 [1024][2048]
#define WS_WCL   4194304u    // cls_w1^T lo
#define WS_WVH   8388608u    // var_w1^T hi
#define WS_LOGP  12582912u   // [16][16384][3] f32
#define WS_VARP  15728640u   // [16][16384] f32
#define WS_WD    70254592u   // dec_w2^T bf16 [3][2048][2048]
#define WS_W1T   95420416u   // dec_w1^T bf16 [3][2048][64]
#define WS_STR   96206848u
#define WS_CNT   96272384u
#define WS_LIST  96272640u
#define WS_NZ    96469248u   // noise bf16 [16384][64]
#define WS_ROWOF 98566400u   // rowOf[16384] int
#define WS_PARTS 98631936u   // LN partials [17152][32][2] f32
#define WS_NEED  103022848u

// ---------------- OLD (fallback) layout, ~45 MB ----------------
#define WO_WCH  0u
#define WO_WCL  4194304u
#define WO_WVH  8388608u
#define WO_WD   12582912u
#define WO_W1T  37748736u
#define WO_LOGP 38535168u
#define WO_VARP 41680896u
#define WO_STR  42729472u
#define WO_CNT  42795008u
#define WO_LIST 42795264u
#define WO_NZ   42991872u

typedef float f32x4 __attribute__((ext_vector_type(4)));
typedef short short8 __attribute__((ext_vector_type(8)));

__device__ __forceinline__ f32x4 MFMA(uint4 a, uint4 b, f32x4 c) {
  return __builtin_amdgcn_mfma_f32_16x16x32_bf16(
      __builtin_bit_cast(short8, a), __builtin_bit_cast(short8, b), c, 0, 0, 0);
}

__device__ __forceinline__ void gload16(const void* g, void* l) {
  __builtin_amdgcn_global_load_lds(
      (const __attribute__((address_space(1))) unsigned int*)g,
      (__attribute__((address_space(3))) unsigned int*)l, 16, 0, 0);
}

__device__ __forceinline__ unsigned short f2b(float f) {
  __hip_bfloat16 h = __float2bfloat16(f);
  return __builtin_bit_cast(unsigned short, h);
}
__device__ __forceinline__ float b2f(unsigned short u) {
  return __bfloat162float(__builtin_bit_cast(__hip_bfloat16, u));
}
__device__ __forceinline__ float siluf(float h) { return h / (1.f + expf(-h)); }

// ---------------- T1: transpose+split router weights ----------------
__global__ __launch_bounds__(256) void t_router_w(
    const float* __restrict__ cls_w1, const float* __restrict__ var_w1,
    unsigned short* __restrict__ wch, unsigned short* __restrict__ wcl,
    unsigned short* __restrict__ wvh) {
  __shared__ float tile[32][33];
  int z = blockIdx.z;
  const float* src = z ? var_w1 : cls_w1;
  int k0 = blockIdx.x * 32, n0 = blockIdx.y * 32;
  int tid = threadIdx.x;
#pragma unroll
  for (int p = 0; p < 4; ++p) {
    int idx = tid + p * 256; int kk = idx >> 5, nn = idx & 31;
    tile[kk][nn] = src[(size_t)(k0 + kk) * HH + (n0 + nn)];
  }
  __syncthreads();
#pragma unroll
  for (int p = 0; p < 4; ++p) {
    int idx = tid + p * 256; int kk = idx & 31, nn = idx >> 5;
    float v = tile[kk][nn];
    size_t o = (size_t)(n0 + nn) * DD + (k0 + kk);
    unsigned short h = f2b(v);
    if (z == 0) { wch[o] = h; wcl[o] = f2b(v - b2f(h)); }
    else        { wvh[o] = h; }
  }
}

// ---------------- T2: transpose dec_w2 -> [e][n][k] bf16 ----------------
__global__ __launch_bounds__(256) void t_dec_w(
    const float* __restrict__ dec_w2, unsigned short* __restrict__ wd) {
  __shared__ float tile[32][33];
  int e = blockIdx.z;
  const float* src = dec_w2 + (size_t)e * DD * DD;
  unsigned short* dst = wd + (size_t)e * DD * DD;
  int k0 = blockIdx.x * 32, n0 = blockIdx.y * 32;
  int tid = threadIdx.x;
#pragma unroll
  for (int p = 0; p < 4; ++p) {
    int idx = tid + p * 256; int kk = idx >> 5, nn = idx & 31;
    tile[kk][nn] = src[(size_t)(k0 + kk) * DD + (n0 + nn)];
  }
  __syncthreads();
#pragma unroll
  for (int p = 0; p < 4; ++p) {
    int idx = tid + p * 256; int kk = idx & 31, nn = idx >> 5;
    dst[(size_t)(n0 + nn) * DD + (k0 + kk)] = f2b(tile[kk][nn]);
  }
}

// ---------------- T3: transpose dec_w1 -> w1t [e][2048][64] bf16 ----------------
__global__ __launch_bounds__(256) void t_dec_w1(
    const float* __restrict__ dec_w1, unsigned short* __restrict__ w1t) {
  __shared__ float tile[32][33];
  int e = blockIdx.z;
  const float* src = dec_w1 + (size_t)e * NDIM * DD;
  unsigned short* dst = w1t + (size_t)e * DD * NDIM;
  int k0 = blockIdx.x * 32, c0 = blockIdx.y * 32;
  int tid = threadIdx.x;
#pragma unroll
  for (int p = 0; p < 4; ++p) {
    int idx = tid + p * 256; int kk = idx >> 5, nn = idx & 31;
    tile[kk][nn] = src[(size_t)(k0 + kk) * DD + (c0 + nn)];
  }
  __syncthreads();
#pragma unroll
  for (int p = 0; p < 4; ++p) {
    int idx = tid + p * 256; int kk = idx & 31, nn = idx >> 5;
    dst[(size_t)(c0 + nn) * NDIM + (k0 + kk)] = f2b(tile[kk][nn]);
  }
}

// ---------------- K1: merged router GEMM (3-term compensated + var) ----------------
// BM=128 tokens, BN=256 cols, 512 threads (8 waves = 2 row-groups x 4 col-waves).
// A in LDS subtiled [g=row/16][kslot][r][8elem]: writes AND b128 reads are each
// a contiguous 1024B span per wave -> conflict-free.
// XCD-affine: nblk = (bx&7)>>1 so each XCD's B slice (3 MB) is L2-resident.
__global__ __launch_bounds__(512) void k_router(
    const float* __restrict__ x,
    const float* __restrict__ cls_b1, const float* __restrict__ cls_w2,
    const float* __restrict__ var_b1, const float* __restrict__ var_w2,
    const unsigned short* __restrict__ wch, const unsigned short* __restrict__ wcl,
    const unsigned short* __restrict__ wvh,
    float* __restrict__ logp, float* __restrict__ varp) {
  __shared__ uint4 AHq[512];   // 8 KB: [8 g][4 kslot][16 r] x 16B
  __shared__ uint4 ALq[512];
  int bx = blockIdx.x;
  int nblk = (bx & 7) >> 1;
  int mt = ((bx >> 3) << 1) | (bx & 1);
  int rowbase = mt * 128;
  int tid = threadIdx.x;
  int lane = tid & 63, wave = tid >> 6;
  int wn = wave & 3, wm = wave >> 2;
  int arl = lane & 15, kg = lane >> 4;
  int colw = nblk * 256 + wn * 64;
  f32x4 accC[4][4], accV[4][4];
#pragma unroll
  for (int a = 0; a < 4; ++a)
#pragma unroll
    for (int b = 0; b < 4; ++b) { accC[a][b] = (f32x4)0.f; accV[a][b] = (f32x4)0.f; }
  int srow = tid >> 2, ks = tid & 3;
  const float* xrow = x + (size_t)(rowbase + srow) * DD + ks * 8;
  int wslot = (srow >> 4) * 64 + ks * 16 + (srow & 15);

  for (int k0 = 0; k0 < DD; k0 += 32) {
    float4 v0 = *(const float4*)(xrow + k0);
    float4 v1 = *(const float4*)(xrow + k0 + 4);
    float vv[8] = {v0.x, v0.y, v0.z, v0.w, v1.x, v1.y, v1.z, v1.w};
    union { unsigned short u[8]; uint4 q; } ph, pl;
#pragma unroll
    for (int j = 0; j < 8; ++j) {
      unsigned short h = f2b(vv[j]);
      ph.u[j] = h;
      pl.u[j] = f2b(vv[j] - b2f(h));
    }
    AHq[wslot] = ph.q;
    ALq[wslot] = pl.q;
    __syncthreads();
    uint4 ah[4], al[4];
#pragma unroll
    for (int rt = 0; rt < 4; ++rt) {
      int slot = (wm * 4 + rt) * 64 + kg * 16 + arl;
      ah[rt] = AHq[slot];
      al[rt] = ALq[slot];
    }
#pragma unroll
    for (int nt = 0; nt < 4; ++nt) {
      int col = colw + nt * 16 + arl;
      size_t bo = (size_t)col * DD + k0 + kg * 8;
      uint4 bh = *(const uint4*)(wch + bo);
      uint4 bl = *(const uint4*)(wcl + bo);
      uint4 bv = *(const uint4*)(wvh + bo);
#pragma unroll
      for (int rt = 0; rt < 4; ++rt) {
        accC[rt][nt] = MFMA(ah[rt], bh, accC[rt][nt]);
        accC[rt][nt] = MFMA(al[rt], bh, accC[rt][nt]);
        accC[rt][nt] = MFMA(ah[rt], bl, accC[rt][nt]);
        accV[rt][nt] = MFMA(ah[rt], bv, accV[rt][nt]);
      }
    }
    __syncthreads();
  }

  float part[4][4][3], pv[4][4];
#pragma unroll
  for (int rt = 0; rt < 4; ++rt)
#pragma unroll
    for (int r = 0; r < 4; ++r) {
      part[rt][r][0] = 0.f; part[rt][r][1] = 0.f; part[rt][r][2] = 0.f;
      pv[rt][r] = 0.f;
    }
#pragma unroll
  for (int nt = 0; nt < 4; ++nt) {
    int colg = colw + nt * 16 + arl;
    float bbc = cls_b1[colg];
    float w0 = cls_w2[colg * 3 + 0];
    float w1v = cls_w2[colg * 3 + 1];
    float w2v = cls_w2[colg * 3 + 2];
    float bbv = var_b1[colg];
    float wv = var_w2[colg];
#pragma unroll
    for (int rt = 0; rt < 4; ++rt)
#pragma unroll
      for (int r = 0; r < 4; ++r) {
        float s = siluf(accC[rt][nt][r] + bbc);
        part[rt][r][0] += s * w0;
        part[rt][r][1] += s * w1v;
        part[rt][r][2] += s * w2v;
        pv[rt][r] += siluf(accV[rt][nt][r] + bbv) * wv;
      }
  }
  for (int m = 1; m < 16; m <<= 1)
#pragma unroll
    for (int rt = 0; rt < 4; ++rt)
#pragma unroll
      for (int r = 0; r < 4; ++r) {
        part[rt][r][0] += __shfl_xor(part[rt][r][0], m);
        part[rt][r][1] += __shfl_xor(part[rt][r][1], m);
        part[rt][r][2] += __shfl_xor(part[rt][r][2], m);
        pv[rt][r] += __shfl_xor(pv[rt][r], m);
      }
  if (arl == 0) {
    int slot = nblk * 4 + wn;
#pragma unroll
    for (int rt = 0; rt < 4; ++rt)
#pragma unroll
      for (int r = 0; r < 4; ++r) {
        int row = rowbase + wm * 64 + rt * 16 + kg * 4 + r;
        size_t o = (size_t)slot * TOK + row;
        logp[o * 3 + 0] = part[rt][r][0];
        logp[o * 3 + 1] = part[rt][r][1];
        logp[o * 3 + 2] = part[rt][r][2];
        varp[o] = pv[rt][r];
      }
  }
}

// ---------------- K2: deterministic reduce + argmax + strength + buckets ----------------
__global__ __launch_bounds__(256) void k_select(
    const float* __restrict__ logp, const float* __restrict__ varp,
    const float* __restrict__ cls_b2, const float* __restrict__ var_b2,
    float* __restrict__ strength, int* __restrict__ cnt, int* __restrict__ list) {
  int t = blockIdx.x * 256 + threadIdx.x;
  if (t >= TOK) return;
  float l0 = cls_b2[0], l1 = cls_b2[1], l2 = cls_b2[2];
  float vv = var_b2[0];
#pragma unroll
  for (int s = 0; s < 16; ++s) {
    size_t o = (size_t)s * TOK + t;
    l0 += logp[o * 3 + 0];
    l1 += logp[o * 3 + 1];
    l2 += logp[o * 3 + 2];
    vv += varp[o];
  }
  int best = 0; float bl = l0;
  if (l1 > bl) { best = 1; bl = l1; }
  if (l2 > bl) { best = 2; bl = l2; }
  int pos = atomicAdd(&cnt[best], 1);
  list[best * TOK + pos] = t;
  strength[t] = 1.f / (1.f + expf(-vv));
}

// ---------------- K3: encoder (selected expert only, bucketed) ----------------
__global__ __launch_bounds__(256) void k_encode(
    const float* __restrict__ x, const float* __restrict__ eps,
    const float* __restrict__ enc_w1, const float* __restrict__ enc_b1,
    const float* __restrict__ enc_w2, const float* __restrict__ enc_b2,
    const int* __restrict__ cnt, const int* __restrict__ list,
    float* __restrict__ out, unsigned short* __restrict__ nzbf) {
  __shared__ unsigned short xl[8][2048];
  __shared__ float part[4][512];
  __shared__ float hls[8][64];
  __shared__ float pls[8][128];
  __shared__ int toks[8];
  __shared__ int es[8];
  int tid = threadIdx.x;
  if (tid < 8) {
    int slot = blockIdx.x * 8 + tid;
    int c0 = cnt[0], c1 = cnt[1];
    int e, idx;
    if (slot < c0)            { e = 0; idx = slot; }
    else if (slot < c0 + c1)  { e = 1; idx = slot - c0; }
    else                      { e = 2; idx = slot - c0 - c1; }
    toks[tid] = list[e * TOK + idx];
    es[tid] = e;
  }
  __syncthreads();
  bool uni = true;
  int e0 = es[0];
#pragma unroll
  for (int r = 1; r < 8; ++r) uni = uni && (es[r] == e0);
#pragma unroll
  for (int r = 0; r < 8; ++r) {
    const float4* xr = (const float4*)(x + (size_t)toks[r] * DD);
#pragma unroll
    for (int i = 0; i < 2; ++i) {
      int kq = tid + i * 256;
      float4 v = xr[kq];
      union { unsigned short u[4]; unsigned long long q; } p;
      p.u[0] = f2b(v.x); p.u[1] = f2b(v.y); p.u[2] = f2b(v.z); p.u[3] = f2b(v.w);
      *(unsigned long long*)(&xl[r][kq * 4]) = p.q;
    }
  }
  __syncthreads();
  int n = tid & 63, q = tid >> 6;
  float acc[8];
#pragma unroll
  for (int r = 0; r < 8; ++r) acc[r] = 0.f;
  if (uni) {
    const float* w = enc_w1 + (size_t)e0 * DD * NDIM;
    for (int kk = 0; kk < 512; ++kk) {
      int k = q * 512 + kk;
      float wv = w[k * NDIM + n];
#pragma unroll
      for (int r = 0; r < 8; ++r) acc[r] += b2f(xl[r][k]) * wv;
    }
  } else {
#pragma unroll
    for (int r = 0; r < 8; ++r) {
      const float* w = enc_w1 + (size_t)es[r] * DD * NDIM;
      float a = 0.f;
      for (int kk = 0; kk < 512; ++kk) {
        int k = q * 512 + kk;
        a += b2f(xl[r][k]) * w[k * NDIM + n];
      }
      acc[r] = a;
    }
  }
#pragma unroll
  for (int r = 0; r < 8; ++r) part[q][r * 64 + n] = acc[r];
  __syncthreads();
#pragma unroll
  for (int it = 0; it < 2; ++it) {
    int o = tid + it * 256; int r = o >> 6, n2 = o & 63; int e = es[r];
    float h = part[0][o] + part[1][o] + part[2][o] + part[3][o] + enc_b1[e * 64 + n2];
    hls[r][n2] = siluf(h);
  }
  __syncthreads();
#pragma unroll
  for (int it = 0; it < 4; ++it) {
    int o = tid + it * 256; int r = o >> 7, j = o & 127; int e = es[r];
    const float* w2 = enc_w2 + e * 64 * 128;
    float a = 0.f;
#pragma unroll
    for (int nn = 0; nn < 64; ++nn) a += hls[r][nn] * w2[nn * 128 + j];
    pls[r][j] = a + enc_b2[e * 128 + j];
  }
  __syncthreads();
#pragma unroll
  for (int it = 0; it < 2; ++it) {
    int o = tid + it * 256; int r = o >> 6, j = o & 63; int t = toks[r];
    float m = pls[r][j], lv = pls[r][64 + j];
    float nz = eps[(size_t)t * 64 + j] * expf(0.5f * lv) + m;
    out[NOISE_OFF + (size_t)t * 64 + j] = nz;
    out[MEAN_OFF + (size_t)t * 64 + j] = m;
    out[LV_OFF + (size_t)t * 64 + j] = lv;
    nzbf[t * 64 + j] = f2b(nz);
  }
}

// ---------------- K4a: dh = silu(noise @ dec_w1 + b1) -> dhg (128-padded, bucket-ordered) ----------------
__global__ __launch_bounds__(512) void k_dh(
    const unsigned short* __restrict__ w1t, const float* __restrict__ dec_b1,
    const unsigned short* __restrict__ nzbf,
    const int* __restrict__ cnt, const int* __restrict__ list,
    unsigned short* __restrict__ dhg, int* __restrict__ rowOf) {
  __shared__ unsigned short dhs[65536];   // [64 ktile][32 row][32 k]
  __shared__ unsigned short nzs[2048];    // [2][32][32]
  __shared__ int tokv[32];
  int tid = threadIdx.x;
  int r0 = blockIdx.x * 32;
  int c0 = cnt[0], c1 = cnt[1], c2 = cnt[2];
  int tb1 = (c0 + 127) & ~127;
  int tb2 = tb1 + ((c1 + 127) & ~127);
  int e, lbase, cd;
  if (r0 < tb1)      { e = 0; lbase = r0;       cd = c0; }
  else if (r0 < tb2) { e = 1; lbase = r0 - tb1; cd = c1; }
  else               { e = 2; lbase = r0 - tb2; cd = c2; }
  if (tid < 32) {
    int idx = lbase + tid;
    int ok = idx < cd && idx >= 0;
    int t = ok ? list[e * TOK + idx] : -1;
    tokv[tid] = t;
    if (ok) rowOf[t] = r0 + tid;
  }
  __syncthreads();
#pragma unroll
  for (int i = 0; i < 4; ++i) {
    int o = tid + i * 512; int r = o >> 6, k = o & 63;
    int t = tokv[r];
    nzs[(k >> 5) * 1024 + r * 32 + (k & 31)] =
        (t >= 0) ? nzbf[(size_t)t * 64 + k] : (unsigned short)0;
  }
  __syncthreads();
  int lane = tid & 63, wave = tid >> 6;
  int arl = lane & 15, kg = lane >> 4;
  int colbase = wave * 256;
  const unsigned short* w1e = w1t + (size_t)e * DD * NDIM;
  const float* b1 = dec_b1 + (size_t)e * DD;
  float b1v[16];
#pragma unroll
  for (int nt = 0; nt < 16; ++nt) b1v[nt] = b1[colbase + nt * 16 + arl];
  f32x4 acch[2][16];
#pragma unroll
  for (int rt = 0; rt < 2; ++rt)
#pragma unroll
    for (int nt = 0; nt < 16; ++nt) acch[rt][nt] = (f32x4)0.f;
#pragma unroll
  for (int h = 0; h < 2; ++h) {
    uint4 a0 = *(const uint4*)&nzs[h * 1024 + arl * 32 + kg * 8];
    uint4 a1 = *(const uint4*)&nzs[h * 1024 + (16 + arl) * 32 + kg * 8];
#pragma unroll
    for (int nt = 0; nt < 16; ++nt) {
      int col = colbase + nt * 16 + arl;
      uint4 b = *(const uint4*)(w1e + (size_t)col * NDIM + h * 32 + kg * 8);
      acch[0][nt] = MFMA(a0, b, acch[0][nt]);
      acch[1][nt] = MFMA(a1, b, acch[1][nt]);
    }
  }
#pragma unroll
  for (int rt = 0; rt < 2; ++rt)
#pragma unroll
    for (int nt = 0; nt < 16; ++nt) {
      int c = colbase + nt * 16 + arl;
#pragma unroll
      for (int r = 0; r < 4; ++r) {
        int row = rt * 16 + kg * 4 + r;
        float s = siluf(acch[rt][nt][r] + b1v[nt]);
        dhs[(c >> 5) * 1024 + row * 32 + (c & 31)] = f2b(s);
      }
    }
  __syncthreads();
  // coalesced copy-out: [row][k] row-major
#pragma unroll
  for (int it = 0; it < 16; ++it) {
    int idx = tid + it * 512;
    int row = idx >> 8, ks8 = idx & 255;
    int k = ks8 * 8;
    uint4 v = *(const uint4*)&dhs[(k >> 5) * 1024 + row * 32 + (k & 31)];
    *(uint4*)&dhg[(size_t)(r0 + row) * DD + k] = v;
  }
}

// ---------------- K4b: grouped GEMM do = dh @ dec_w2^T (+b2) ----------------
// 128x256 tile, KC=32, 512 thr (8 waves = 2 wm x 4 wn), LDS 48KB -> 2 blocks/CU.
// nslice = bx&7 (XCD-affine N-slice; 1MB/expert L2-hot). Subtiled LDS layout:
// [g=row/16][kslot][r][16B] -> gload_lds dest AND b128 reads both contiguous
// 1024B per wave (conflict-free).
__global__ __launch_bounds__(512) void k_gemm(
    const unsigned short* __restrict__ dhg, const unsigned short* __restrict__ wd,
    const float* __restrict__ dec_b2,
    const int* __restrict__ cnt, const int* __restrict__ list,
    float* __restrict__ out, float* __restrict__ parts) {
  __shared__ uint4 As4[2][512];    // 128 rows x 32 k
  __shared__ uint4 Bs4[2][1024];   // 256 cols x 32 k
  __shared__ int tokv[128];
  int tid = threadIdx.x;
  int bx = blockIdx.x;
  int nslice = bx & 7, tile = bx >> 3;
  int c0 = cnt[0], c1 = cnt[1], c2 = cnt[2];
  int t0 = (c0 + 127) >> 7, t1 = (c1 + 127) >> 7, t2 = (c2 + 127) >> 7;
  if (tile >= t0 + t1 + t2) return;
  int e, lbase, cd;
  if (tile < t0)           { e = 0; lbase = tile * 128;             cd = c0; }
  else if (tile < t0 + t1) { e = 1; lbase = (tile - t0) * 128;      cd = c1; }
  else                     { e = 2; lbase = (tile - t0 - t1) * 128; cd = c2; }
  int rp0 = tile * 128;
  if (tid < 128) {
    int idx = lbase + tid;
    tokv[tid] = (idx < cd) ? list[e * TOK + idx] : -1;
  }
  const unsigned short* Ag = dhg + (size_t)rp0 * DD;
  const unsigned short* Bg = wd + (size_t)e * DD * DD + (size_t)(nslice * 256) * DD;
  int lane = tid & 63, wave = tid >> 6;
  int wm = wave >> 2, wn = wave & 3;
  int arl = lane & 15, kg = lane >> 4;
  // staging slots: A = tid (512 slots), B = tid and tid+512 (1024 slots)
  int srA = ((tid >> 6) << 4) | (tid & 15);
  int skA = (tid >> 4) & 3;
#define STAGE(h, k0)                                                         \
  {                                                                          \
    gload16(Ag + (size_t)srA * DD + (k0) + skA * 8,                          \
            (char*)&As4[h][0] + tid * 16);                                   \
    gload16(Bg + (size_t)srA * DD + (k0) + skA * 8,                          \
            (char*)&Bs4[h][0] + tid * 16);                                   \
    gload16(Bg + (size_t)(srA + 128) * DD + (k0) + skA * 8,                  \
            (char*)&Bs4[h][0] + (tid + 512) * 16);                           \
  }
  f32x4 acc[4][4];
#pragma unroll
  for (int mt = 0; mt < 4; ++mt)
#pragma unroll
    for (int nt = 0; nt < 4; ++nt) acc[mt][nt] = (f32x4)0.f;
  STAGE(0, 0);
  __syncthreads();
  for (int t = 0; t < 64; ++t) {
    int cur = t & 1;
    if (t < 63) STAGE(cur ^ 1, (t + 1) * 32);
    uint4 bfr[4];
#pragma unroll
    for (int nt = 0; nt < 4; ++nt)
      bfr[nt] = Bs4[cur][(wn * 4 + nt) * 64 + kg * 16 + arl];
#pragma unroll
    for (int mt = 0; mt < 4; ++mt) {
      uint4 afr = As4[cur][(wm * 4 + mt) * 64 + kg * 16 + arl];
#pragma unroll
      for (int nt = 0; nt < 4; ++nt)
        acc[mt][nt] = MFMA(afr, bfr[nt], acc[mt][nt]);
    }
    __syncthreads();
  }
#undef STAGE
  // ---- epilogue: +b2, store do to out[token], write LN partials ----
  const float* b2 = dec_b2 + (size_t)e * DD + nslice * 256;
  float b2v[4];
#pragma unroll
  for (int nt = 0; nt < 4; ++nt) b2v[nt] = b2[wn * 64 + nt * 16 + arl];
  int sl = (nslice * 4 + wn) * 2;
#pragma unroll
  for (int mt = 0; mt < 4; ++mt) {
#pragma unroll
    for (int rr = 0; rr < 4; ++rr) {
      int row = wm * 64 + mt * 16 + kg * 4 + rr;
      int token = tokv[row];
      float s1 = 0.f, s2 = 0.f;
      float v[4];
#pragma unroll
      for (int nt = 0; nt < 4; ++nt) {
        v[nt] = acc[mt][nt][rr] + b2v[nt];
        s1 += v[nt];
        s2 += v[nt] * v[nt];
      }
      if (token >= 0) {
        size_t o = (size_t)token * DD + nslice * 256 + wn * 64 + arl;
#pragma unroll
        for (int nt = 0; nt < 4; ++nt) out[o + nt * 16] = v[nt];
      }
#pragma unroll
      for (int m = 1; m < 16; m <<= 1) {
        s1 += __shfl_xor(s1, m);
        s2 += __shfl_xor(s2, m);
      }
      if (arl == 0) {
        size_t po = (size_t)(rp0 + row) * 64 + sl;
        parts[po] = s1;
        parts[po + 1] = s2;
      }
    }
  }
}

// ---------------- K4c: row LayerNorm + gain/bias + strength*residual ----------------
__global__ __launch_bounds__(256) void k_ln(
    const float* __restrict__ x, const float* __restrict__ ln_g,
    const float* __restrict__ ln_b, const float* __restrict__ strength,
    const int* __restrict__ rowOf, const float* __restrict__ parts,
    const int* __restrict__ cnt, float* __restrict__ out) {
  int wave = threadIdx.x >> 6, lane = threadIdx.x & 63;
  int t = blockIdx.x * 4 + wave;
  int rp = rowOf[t];
  int c0 = cnt[0], c1 = cnt[1];
  int tb1 = (c0 + 127) & ~127;
  int tb2 = tb1 + ((c1 + 127) & ~127);
  int e = rp < tb1 ? 0 : (rp < tb2 ? 1 : 2);
  float s1 = 0.f, s2 = 0.f;
#pragma unroll
  for (int i = 0; i < 32; ++i) {
    s1 += parts[(size_t)rp * 64 + i * 2];
    s2 += parts[(size_t)rp * 64 + i * 2 + 1];
  }
  float mu = s1 * (1.f / 2048.f);
  float var = s2 * (1.f / 2048.f) - mu * mu;
  float rs = rsqrtf(var + 1e-5f);
  float str = strength[t];
  size_t o = (size_t)t * DD;
#pragma unroll
  for (int i = 0; i < 8; ++i) {
    int col = i * 256 + lane * 4;
    float4 v = *(const float4*)&out[o + col];
    float4 xv = *(const float4*)&x[o + col];
    float4 g = *(const float4*)&ln_g[(size_t)e * DD + col];
    float4 b = *(const float4*)&ln_b[(size_t)e * DD + col];
    float4 r;
    r.x = xv.x + str * ((v.x - mu) * rs * g.x + b.x);
    r.y = xv.y + str * ((v.y - mu) * rs * g.y + b.y);
    r.z = xv.z + str * ((v.z - mu) * rs * g.z + b.z);
    r.w = xv.w + str * ((v.w - mu) * rs * g.w + b.w);
    *(float4*)&out[o + col] = r;
  }
}

// ---------------- K4 (fallback): round-3 monolithic decoder ----------------
__global__ __launch_bounds__(512, 2) void k_decode_old(
    const float* __restrict__ x,
    const float* __restrict__ dec_b1, const float* __restrict__ dec_b2,
    const float* __restrict__ ln_g, const float* __restrict__ ln_b,
    const unsigned short* __restrict__ w1t, const unsigned short* __restrict__ wd,
    const unsigned short* __restrict__ nzbf,
    const int* __restrict__ cnt, const int* __restrict__ list,
    const float* __restrict__ strength, float* __restrict__ out) {
  int bx = blockIdx.x;
  int x7 = bx & 7;
  int e = (x7 * 3) >> 3;
  int idx = x7 - (e == 0 ? 0 : (e == 1 ? 3 : 6));
  int we = (e == 2) ? 2 : 3;
  int mt = (bx >> 3) * we + idx;
  int cnte = cnt[e];
  int base = mt * 32;
  if (base >= cnte) return;
  __shared__ unsigned short dhs[65536];
  __shared__ unsigned short nzs[2048];
  __shared__ float sums[32][2];
  __shared__ int tokv[32];
  __shared__ int vld[32];
  int tid = threadIdx.x;
  int lane = tid & 63, wave = tid >> 6;
  int arl = lane & 15, kg = lane >> 4;
  int colbase = wave * 256;
  if (tid < 32) {
    int s = base + tid;
    int ok = (s < cnte) ? 1 : 0;
    vld[tid] = ok;
    tokv[tid] = list[e * TOK + (ok ? s : base)];
  }
  __syncthreads();
#pragma unroll
  for (int i = 0; i < 4; ++i) {
    int o = tid + i * 512; int r = o >> 6, k = o & 63;
    nzs[(k >> 5) * 1024 + r * 32 + (k & 31)] = nzbf[(size_t)tokv[r] * 64 + k];
  }
  __syncthreads();
  const unsigned short* w1e = w1t + (size_t)e * DD * NDIM;
  const float* b1 = dec_b1 + (size_t)e * DD;
  float b1v[16];
#pragma unroll
  for (int nt = 0; nt < 16; ++nt) b1v[nt] = b1[colbase + nt * 16 + arl];
  {
    f32x4 acch[2][16];
#pragma unroll
    for (int rt = 0; rt < 2; ++rt)
#pragma unroll
      for (int nt = 0; nt < 16; ++nt) acch[rt][nt] = (f32x4)0.f;
#pragma unroll
    for (int h = 0; h < 2; ++h) {
      uint4 a0 = *(const uint4*)&nzs[h * 1024 + arl * 32 + kg * 8];
      uint4 a1 = *(const uint4*)&nzs[h * 1024 + (16 + arl) * 32 + kg * 8];
#pragma unroll
      for (int nt = 0; nt < 16; ++nt) {
        int col = colbase + nt * 16 + arl;
        uint4 b = *(const uint4*)(w1e + (size_t)col * NDIM + h * 32 + kg * 8);
        acch[0][nt] = MFMA(a0, b, acch[0][nt]);
        acch[1][nt] = MFMA(a1, b, acch[1][nt]);
      }
    }
#pragma unroll
    for (int rt = 0; rt < 2; ++rt)
#pragma unroll
      for (int nt = 0; nt < 16; ++nt) {
        int c = colbase + nt * 16 + arl;
#pragma unroll
        for (int r = 0; r < 4; ++r) {
          int row = rt * 16 + kg * 4 + r;
          float s = siluf(acch[rt][nt][r] + b1v[nt]);
          dhs[(c >> 5) * 1024 + row * 32 + (c & 31)] = f2b(s);
        }
      }
  }
  __syncthreads();
  const unsigned short* Bt = wd + (size_t)e * DD * DD;
  f32x4 acc[2][16];
#pragma unroll
  for (int rt = 0; rt < 2; ++rt)
#pragma unroll
    for (int nt = 0; nt < 16; ++nt) acc[rt][nt] = (f32x4)0.f;
  for (int k0 = 0; k0 < DD; k0 += 32) {
    int tilo = (k0 >> 5) * 1024;
    uint4 af0 = *(const uint4*)&dhs[tilo + arl * 32 + kg * 8];
    uint4 af1 = *(const uint4*)&dhs[tilo + (16 + arl) * 32 + kg * 8];
    int kb = k0 + kg * 8;
#pragma unroll
    for (int nt = 0; nt < 16; ++nt) {
      int col = colbase + nt * 16 + arl;
      uint4 b = *(const uint4*)(Bt + (size_t)col * DD + kb);
      acc[0][nt] = MFMA(af0, b, acc[0][nt]);
      acc[1][nt] = MFMA(af1, b, acc[1][nt]);
    }
  }
  __syncthreads();
  if (tid < 64) sums[tid >> 1][tid & 1] = 0.f;
  __syncthreads();
  const float* b2 = dec_b2 + (size_t)e * DD;
  float s1[2][4], s2[2][4];
#pragma unroll
  for (int rt = 0; rt < 2; ++rt)
#pragma unroll
    for (int r = 0; r < 4; ++r) { s1[rt][r] = 0.f; s2[rt][r] = 0.f; }
#pragma unroll
  for (int nt = 0; nt < 16; ++nt) {
    int col = colbase + nt * 16 + arl;
    float bbv = b2[col];
#pragma unroll
    for (int rt = 0; rt < 2; ++rt)
#pragma unroll
      for (int r = 0; r < 4; ++r) {
        float v = acc[rt][nt][r] + bbv;
        acc[rt][nt][r] = v;
        s1[rt][r] += v;
        s2[rt][r] += v * v;
      }
  }
  for (int m = 1; m < 16; m <<= 1)
#pragma unroll
    for (int rt = 0; rt < 2; ++rt)
#pragma unroll
      for (int r = 0; r < 4; ++r) {
        s1[rt][r] += __shfl_xor(s1[rt][r], m);
        s2[rt][r] += __shfl_xor(s2[rt][r], m);
      }
  if (arl == 0) {
#pragma unroll
    for (int rt = 0; rt < 2; ++rt)
#pragma unroll
      for (int r = 0; r < 4; ++r) {
        int row = rt * 16 + kg * 4 + r;
        atomicAdd(&sums[row][0], s1[rt][r]);
        atomicAdd(&sums[row][1], s2[rt][r]);
      }
  }
  __syncthreads();
  float mu[2][4], rs[2][4], strv[2][4]; size_t xoff[2][4]; int okr[2][4];
#pragma unroll
  for (int rt = 0; rt < 2; ++rt)
#pragma unroll
    for (int r = 0; r < 4; ++r) {
      int row = rt * 16 + kg * 4 + r;
      float m1 = sums[row][0] * (1.f / 2048.f);
      float var = sums[row][1] * (1.f / 2048.f) - m1 * m1;
      mu[rt][r] = m1;
      rs[rt][r] = rsqrtf(var + 1e-5f);
      int tt = tokv[row];
      okr[rt][r] = vld[row];
      strv[rt][r] = strength[tt];
      xoff[rt][r] = (size_t)tt * DD;
    }
#pragma unroll
  for (int nt = 0; nt < 16; ++nt) {
    int col = colbase + nt * 16 + arl;
    float g = ln_g[e * DD + col], bv = ln_b[e * DD + col];
#pragma unroll
    for (int rt = 0; rt < 2; ++rt)
#pragma unroll
      for (int r = 0; r < 4; ++r) {
        if (okr[rt][r]) {
          float nvv = (acc[rt][nt][r] - mu[rt][r]) * rs[rt][r];
          out[xoff[rt][r] + col] = x[xoff[rt][r] + col] + strv[rt][r] * (nvv * g + bv);
        }
      }
  }
}

// ---------------- launch ----------------
extern "C" void kernel_launch(void* const* d_in, const int* in_sizes, int n_in,
                              void* d_out, int out_size, void* d_ws, size_t ws_size,
                              hipStream_t stream) {
  const float* x      = (const float*)d_in[0];
  const float* eps    = (const float*)d_in[1];
  const float* cls_w1 = (const float*)d_in[2];
  const float* cls_b1 = (const float*)d_in[3];
  const float* cls_w2 = (const float*)d_in[4];
  const float* cls_b2 = (const float*)d_in[5];
  const float* var_w1 = (const float*)d_in[6];
  const float* var_b1 = (const float*)d_in[7];
  const float* var_w2 = (const float*)d_in[8];
  const float* var_b2 = (const float*)d_in[9];
  const float* enc_w1 = (const float*)d_in[10];
  const float* enc_b1 = (const float*)d_in[11];
  const float* enc_w2 = (const float*)d_in[12];
  const float* enc_b2 = (const float*)d_in[13];
  const float* dec_w1 = (const float*)d_in[14];
  const float* dec_b1 = (const float*)d_in[15];
  const float* dec_w2 = (const float*)d_in[16];
  const float* dec_b2 = (const float*)d_in[17];
  const float* ln_g   = (const float*)d_in[18];
  const float* ln_b   = (const float*)d_in[19];
  float* out = (float*)d_out;
  char* ws = (char*)d_ws;
  bool big = ws_size >= (size_t)WS_NEED;

  unsigned short* wch  = (unsigned short*)(ws + (big ? WS_WCH  : WO_WCH));
  unsigned short* wcl  = (unsigned short*)(ws + (big ? WS_WCL  : WO_WCL));
  unsigned short* wvh  = (unsigned short*)(ws + (big ? WS_WVH  : WO_WVH));
  unsigned short* wd   = (unsigned short*)(ws + (big ? WS_WD   : WO_WD));
  unsigned short* w1t  = (unsigned short*)(ws + (big ? WS_W1T  : WO_W1T));
  float* logp = (float*)(ws + (big ? WS_LOGP : WO_LOGP));
  float* varp = (float*)(ws + (big ? WS_VARP : WO_VARP));
  float* str  = (float*)(ws + (big ? WS_STR  : WO_STR));
  int* cnt    = (int*)(ws + (big ? WS_CNT  : WO_CNT));
  int* list   = (int*)(ws + (big ? WS_LIST : WO_LIST));
  unsigned short* nzbf = (unsigned short*)(ws + (big ? WS_NZ : WO_NZ));

  hipMemsetAsync(cnt, 0, 256, stream);

  hipLaunchKernelGGL(t_router_w, dim3(64, 32, 2), dim3(256), 0, stream,
                     cls_w1, var_w1, wch, wcl, wvh);
  hipLaunchKernelGGL(t_dec_w, dim3(64, 64, 3), dim3(256), 0, stream, dec_w2, wd);
  hipLaunchKernelGGL(t_dec_w1, dim3(2, 64, 3), dim3(256), 0, stream, dec_w1, w1t);
  hipLaunchKernelGGL(k_router, dim3(512), dim3(512), 0, stream,
                     x, cls_b1, cls_w2, var_b1, var_w2, wch, wcl, wvh, logp, varp);
  hipLaunchKernelGGL(k_select, dim3(64), dim3(256), 0, stream,
                     logp, varp, cls_b2, var_b2, str, cnt, list);
  hipLaunchKernelGGL(k_encode, dim3(2048), dim3(256), 0, stream,
                     x, eps, enc_w1, enc_b1, enc_w2, enc_b2, cnt, list, out, nzbf);
  if (big) {
    unsigned short* dhg = (unsigned short*)(ws + WS_DHG);
    int* rowOf = (int*)(ws + WS_ROWOF);
    float* parts = (float*)(ws + WS_PARTS);
    hipLaunchKernelGGL(k_dh, dim3(528), dim3(512), 0, stream,
                       w1t, dec_b1, nzbf, cnt, list, dhg, rowOf);
    hipLaunchKernelGGL(k_gemm, dim3(1048), dim3(512), 0, stream,
                       dhg, wd, dec_b2, cnt, list, out, parts);
    hipLaunchKernelGGL(k_ln, dim3(4096), dim3(256), 0, stream,
                       x, ln_g, ln_b, str, rowOf, parts, cnt, out);
  } else {
    hipLaunchKernelGGL(k_decode_old, dim3(2048), dim3(512), 0, stream,
                       x, dec_b1, dec_b2, ln_g, ln_b, w1t, wd, nzbf, cnt, list, str, out);
  }
}